// Round 3
// baseline (73.764 us; speedup 1.0000x reference)
//
#include <hip/hip_runtime.h>

#define DEV static __device__ __forceinline__

typedef __bf16 bf16x8 __attribute__((ext_vector_type(8)));
typedef float  f32x16 __attribute__((ext_vector_type(16)));

// 32x32 MFMA C/D row for reg r, lane-half hi (verified m74/m101)
DEV int rowmap(int r, int hi) { return (r & 3) + 8 * (r >> 2) + 4 * hi; }

// 256B-row tiles (W^T, QL): 16B-block XOR4 swizzle (full bank spread)
DEV int swzQ(int row, int col) {
  return row * 256 + (((((col >> 3) ^ (row & 15)) << 3) | (col & 7)) << 1);
}
// 512B-row tile (V^T [128 d][256 k]): XOR5
DEV int swzV(int d, int k) {
  return d * 512 + (((((k >> 3) ^ (d & 31)) << 3) | (k & 7)) << 1);
}

DEV unsigned pack2(float lo, float hi) {
  union { __bf16 h[2]; unsigned u; } x;
  x.h[0] = (__bf16)lo; x.h[1] = (__bf16)hi;
  return x.u;
}

// D-layout 16-row slab (regs 0..7 or 8..15) -> A/B fragment covering the slab;
// half-swap via shfl_xor(.,32)+select. Lane keeps its column; elements = rows.
DEV bf16x8 mk_frag(float d0, float d1, float d2, float d3,
                   float d4, float d5, float d6, float d7, int lane) {
  unsigned a0 = pack2(d0, d1), a1 = pack2(d2, d3);
  unsigned b0 = pack2(d4, d5), b1 = pack2(d6, d7);
  unsigned a0s = __shfl_xor(a0, 32), a1s = __shfl_xor(a1, 32);
  unsigned b0s = __shfl_xor(b0, 32), b1s = __shfl_xor(b1, 32);
  bool lo = lane < 32;
  union { unsigned u[4]; bf16x8 v; } r;
  r.u[0] = lo ? a0  : b0s;
  r.u[1] = lo ? a1  : b1s;
  r.u[2] = lo ? a0s : b0;
  r.u[3] = lo ? a1s : b1;
  return r.v;
}

DEV f32x16 fzero() {
  f32x16 z;
  #pragma unroll
  for (int i = 0; i < 16; ++i) z[i] = 0.f;
  return z;
}

// async global->LDS, 16B per lane, wave-uniform LDS base (m97 pattern)
DEV void gld16(const char* g, char* l) {
  __builtin_amdgcn_global_load_lds(
      (const __attribute__((address_space(1))) void*)g,
      (__attribute__((address_space(3))) void*)l, 16, 0, 0);
}

// fallback: stage fp32 W (row-major [e][d']) into LDS as swizzled W^T bf16
DEV void stage_w32(const float* __restrict__ W, char* dst, int tid) {
  #pragma unroll
  for (int it = 0; it < 32; ++it) {
    int idx = tid + it * 512;
    int e = idx >> 7, dp = idx & 127;
    *reinterpret_cast<__bf16*>(dst + swzQ(dp, e)) = (__bf16)W[idx];
  }
}

// prep: W fp32 [e][d'] -> bf16 W^T swizzled, packed [Wk|Wq|Wv|Wo] in d_ws
__global__ void prep_wt(const float* __restrict__ Wk, const float* __restrict__ Wq,
                        const float* __restrict__ Wv, const float* __restrict__ Wo,
                        __bf16* __restrict__ wt) {
  int idx = blockIdx.x * 256 + threadIdx.x;   // 0..65535
  const float* W[4] = {Wk, Wq, Wv, Wo};
  int m = idx >> 14, rem = idx & 16383;
  int e = rem >> 7, dp = rem & 127;           // read W[e][dp], coalesced in dp
  wt[m * 16384 + (swzQ(dp, e) >> 1)] = (__bf16)W[m][rem];
}

template<bool WS>
__global__ __launch_bounds__(512, 2)
void sapd_fused(const float* __restrict__ S,
                const float* __restrict__ bq, const float* __restrict__ bk,
                const float* __restrict__ bv, const float* __restrict__ bo,
                const float* __restrict__ Wq, const float* __restrict__ Wk,
                const float* __restrict__ Wv, const float* __restrict__ Wo,
                const float* __restrict__ lg, const float* __restrict__ lb,
                const __bf16* __restrict__ wt,
                float* __restrict__ out)
{
  extern __shared__ char smem[];
  char* QL = smem;           // 64K: prologue Wv(lo)|free(hi) -> Q [256][128] -> Wo(lo)
  char* VT = smem + 65536;   // 64K: prologue Wk(lo)|Wq(hi) -> V^T [128][256]

  const int tid  = threadIdx.x;
  const int lane = tid & 63;
  const int w    = tid >> 6;    // wave 0..7 owns output rows [32w, 32w+32)
  const int ml   = lane & 31;
  const int hi   = lane >> 5;
  const size_t sbase = (size_t)blockIdx.x * (256 * 128);
  const char* wsc = (const char*)wt;

  // ---- stage Wk|Wq -> VT, Wv -> QL.lo (96 chunks of 1KB, DMA, no reg trip) ----
  if (WS) {
    #pragma unroll
    for (int j = 0; j < 12; ++j) {
      int c = w + 8 * j;  // wave-uniform
      char* dst = (c < 64) ? (VT + c * 1024) : (QL + (c - 64) * 1024);
      gld16(wsc + c * 1024 + lane * 16, dst);
    }
  } else {
    stage_w32(Wk, VT, tid);
    stage_w32(Wq, VT + 32768, tid);
    stage_w32(Wv, QL, tid);
  }

  // ---- S row-fragments (A/B operand for the three projections) ----
  bf16x8 sfrag[8];
  {
    const float* srow = S + sbase + (size_t)(32 * w + ml) * 128;
    #pragma unroll
    for (int kk = 0; kk < 8; ++kk) {
      float4 a = *reinterpret_cast<const float4*>(srow + 16 * kk + 8 * hi);
      float4 b = *reinterpret_cast<const float4*>(srow + 16 * kk + 8 * hi + 4);
      bf16x8 f;
      f[0] = (__bf16)a.x; f[1] = (__bf16)a.y; f[2] = (__bf16)a.z; f[3] = (__bf16)a.w;
      f[4] = (__bf16)b.x; f[5] = (__bf16)b.y; f[6] = (__bf16)b.z; f[7] = (__bf16)b.w;
      sfrag[kk] = f;
    }
  }
  __syncthreads();  // #1: Wk|Wq|Wv staged

  // ---- K-proj SWAPPED: accK = K^T tile (lane = j = 32w+ml, rows = d' slab) ----
  f32x16 accK[4];
  #pragma unroll
  for (int t = 0; t < 4; ++t) accK[t] = fzero();
  #pragma unroll
  for (int kk = 0; kk < 8; ++kk) {
    #pragma unroll
    for (int t = 0; t < 4; ++t) {
      bf16x8 wf = *reinterpret_cast<const bf16x8*>(
          VT + swzQ(32 * t + ml, 16 * kk + 8 * hi));
      accK[t] = __builtin_amdgcn_mfma_f32_32x32x16_bf16(wf, sfrag[kk], accK[t], 0, 0, 0);
    }
  }
  bf16x8 kfrag[8];
  #pragma unroll
  for (int t = 0; t < 4; ++t) {
    #pragma unroll
    for (int r = 0; r < 16; ++r) accK[t][r] += bk[32 * t + rowmap(r, hi)];
    kfrag[2 * t]     = mk_frag(accK[t][0], accK[t][1], accK[t][2], accK[t][3],
                               accK[t][4], accK[t][5], accK[t][6], accK[t][7], lane);
    kfrag[2 * t + 1] = mk_frag(accK[t][8], accK[t][9], accK[t][10], accK[t][11],
                               accK[t][12], accK[t][13], accK[t][14], accK[t][15], lane);
  }

  // ---- Q-proj normal (rows = own k-rows, cols = d'), hold in regs ----
  f32x16 accQ[4];
  #pragma unroll
  for (int t = 0; t < 4; ++t) accQ[t] = fzero();
  #pragma unroll
  for (int kk = 0; kk < 8; ++kk) {
    #pragma unroll
    for (int t = 0; t < 4; ++t) {
      bf16x8 wf = *reinterpret_cast<const bf16x8*>(
          VT + 32768 + swzQ(32 * t + ml, 16 * kk + 8 * hi));
      accQ[t] = __builtin_amdgcn_mfma_f32_32x32x16_bf16(sfrag[kk], wf, accQ[t], 0, 0, 0);
    }
  }

  // ---- V-proj normal, hold in regs ----
  f32x16 accV[4];
  #pragma unroll
  for (int t = 0; t < 4; ++t) accV[t] = fzero();
  #pragma unroll
  for (int kk = 0; kk < 8; ++kk) {
    #pragma unroll
    for (int t = 0; t < 4; ++t) {
      bf16x8 wf = *reinterpret_cast<const bf16x8*>(
          QL + swzQ(32 * t + ml, 16 * kk + 8 * hi));
      accV[t] = __builtin_amdgcn_mfma_f32_32x32x16_bf16(sfrag[kk], wf, accV[t], 0, 0, 0);
    }
  }
  __syncthreads();  // #2: all waves done reading W tiles

  // ---- write Q rows -> QL, V^T -> VT ----
  #pragma unroll
  for (int t = 0; t < 4; ++t) {
    float bb = bq[32 * t + ml];
    #pragma unroll
    for (int r = 0; r < 16; ++r)
      *reinterpret_cast<__bf16*>(
          QL + swzQ(32 * w + rowmap(r, hi), 32 * t + ml)) =
          (__bf16)(accQ[t][r] + bb);
  }
  #pragma unroll
  for (int t = 0; t < 4; ++t) {
    float bb = bv[32 * t + ml];
    int d = 32 * t + ml;
    #pragma unroll
    for (int p = 0; p < 8; ++p) {
      int k = 32 * w + rowmap(2 * p, hi);  // even; pair (k, k+1)
      *reinterpret_cast<unsigned*>(VT + swzV(d, k)) =
          pack2(accV[t][2 * p] + bb, accV[t][2 * p + 1] + bb);
    }
  }
  __syncthreads();  // #3: Q + V^T visible

  // ---- attention: sa = scores (lane=j, rows=kappa), relu, ctx^T += V^T·P^T ----
  f32x16 ctx[4];
  #pragma unroll
  for (int m = 0; m < 4; ++m) ctx[m] = fzero();
  const float SC = 0.088388347648318447f;  // 1/sqrt(128)

  #pragma unroll 4
  for (int kt = 0; kt < 8; ++kt) {
    f32x16 sa = fzero();
    #pragma unroll
    for (int kk = 0; kk < 8; ++kk) {
      bf16x8 qf = *reinterpret_cast<const bf16x8*>(
          QL + swzQ(32 * kt + ml, 16 * kk + 8 * hi));
      sa = __builtin_amdgcn_mfma_f32_32x32x16_bf16(qf, kfrag[kk], sa, 0, 0, 0);
    }
    float p[16];
    #pragma unroll
    for (int r = 0; r < 16; ++r) p[r] = fmaxf(sa[r] * SC, 0.f);
    bf16x8 pf0 = mk_frag(p[0], p[1], p[2], p[3], p[4], p[5], p[6], p[7], lane);
    bf16x8 pf1 = mk_frag(p[8], p[9], p[10], p[11], p[12], p[13], p[14], p[15], lane);
    #pragma unroll
    for (int m = 0; m < 4; ++m) {
      bf16x8 vf0 = *reinterpret_cast<const bf16x8*>(
          VT + swzV(32 * m + ml, 32 * kt + 8 * hi));
      ctx[m] = __builtin_amdgcn_mfma_f32_32x32x16_bf16(vf0, pf0, ctx[m], 0, 0, 0);
      bf16x8 vf1 = *reinterpret_cast<const bf16x8*>(
          VT + swzV(32 * m + ml, 32 * kt + 16 + 8 * hi));
      ctx[m] = __builtin_amdgcn_mfma_f32_32x32x16_bf16(vf1, pf1, ctx[m], 0, 0, 0);
    }
  }

  // ---- ctx^T -> A-frags; stage Wo into QL.lo; prefetch residual ----
  bf16x8 cf[8];
  #pragma unroll
  for (int m = 0; m < 4; ++m) {
    cf[2 * m]     = mk_frag(ctx[m][0], ctx[m][1], ctx[m][2], ctx[m][3],
                            ctx[m][4], ctx[m][5], ctx[m][6], ctx[m][7], lane);
    cf[2 * m + 1] = mk_frag(ctx[m][8], ctx[m][9], ctx[m][10], ctx[m][11],
                            ctx[m][12], ctx[m][13], ctx[m][14], ctx[m][15], lane);
  }
  __syncthreads();  // #4: everyone done reading QL (Q dead)
  if (WS) {
    #pragma unroll
    for (int j = 0; j < 4; ++j) {
      int c = w + 8 * j;
      gld16(wsc + 98304 + c * 1024 + lane * 16, QL + c * 1024);
    }
  } else {
    stage_w32(Wo, QL, tid);
  }
  float resv[4][16];
  #pragma unroll
  for (int t = 0; t < 4; ++t) {
    #pragma unroll
    for (int r = 0; r < 16; ++r)
      resv[t][r] = S[sbase + (size_t)(32 * w + rowmap(r, hi)) * 128 + 32 * t + ml];
  }
  __syncthreads();  // #5: Wo visible (residual loads drained here too)

  // ---- out-proj ----
  f32x16 oa[4];
  #pragma unroll
  for (int t = 0; t < 4; ++t) oa[t] = fzero();
  #pragma unroll
  for (int kk = 0; kk < 8; ++kk) {
    #pragma unroll
    for (int t = 0; t < 4; ++t) {
      bf16x8 wf = *reinterpret_cast<const bf16x8*>(
          QL + swzQ(32 * t + ml, 16 * kk + 8 * hi));
      oa[t] = __builtin_amdgcn_mfma_f32_32x32x16_bf16(cf[kk], wf, oa[t], 0, 0, 0);
    }
  }

  // ---- epilogue: +bo, +residual(fp32), LayerNorm, store ----
  float gg[4], lbv[4], bov[4];
  #pragma unroll
  for (int t = 0; t < 4; ++t) {
    gg[t]  = lg[32 * t + ml];
    lbv[t] = lb[32 * t + ml];
    bov[t] = bo[32 * t + ml];
  }
  float sum[16], ssq[16];
  #pragma unroll
  for (int r = 0; r < 16; ++r) { sum[r] = 0.f; ssq[r] = 0.f; }
  #pragma unroll
  for (int t = 0; t < 4; ++t) {
    #pragma unroll
    for (int r = 0; r < 16; ++r) {
      float x = oa[t][r] + bov[t] + resv[t][r];
      oa[t][r] = x;
      sum[r] += x;
      ssq[r] += x * x;
    }
  }
  #pragma unroll
  for (int r = 0; r < 16; ++r) {
    float s_ = sum[r], q_ = ssq[r];
    #pragma unroll
    for (int m = 1; m <= 16; m <<= 1) {
      s_ += __shfl_xor(s_, m);
      q_ += __shfl_xor(q_, m);
    }
    float mu = s_ * (1.f / 128.f);
    float var = q_ * (1.f / 128.f) - mu * mu;
    float rs = rsqrtf(var + 1e-5f);
    float* orow = out + sbase + (size_t)(32 * w + rowmap(r, hi)) * 128;
    #pragma unroll
    for (int t = 0; t < 4; ++t)
      orow[32 * t + ml] = (oa[t][r] - mu) * rs * gg[t] + lbv[t];
  }
}

extern "C" void kernel_launch(void* const* d_in, const int* in_sizes, int n_in,
                              void* d_out, int out_size, void* d_ws, size_t ws_size,
                              hipStream_t stream) {
  (void)in_sizes; (void)n_in; (void)out_size;
  const float* S  = (const float*)d_in[1];
  const float* Wq = (const float*)d_in[2];
  const float* bq = (const float*)d_in[3];
  const float* Wk = (const float*)d_in[4];
  const float* bk = (const float*)d_in[5];
  const float* Wv = (const float*)d_in[6];
  const float* bv = (const float*)d_in[7];
  const float* Wo = (const float*)d_in[8];
  const float* bo = (const float*)d_in[9];
  const float* lg = (const float*)d_in[10];
  const float* lb = (const float*)d_in[11];
  float* out = (float*)d_out;

  constexpr int SMEM = 131072;  // 128 KiB dynamic LDS -> 1 block/CU (LDS-capped)
  bool use_ws = (d_ws != nullptr) && (ws_size >= 131072);
  if (use_ws) {
    prep_wt<<<dim3(256), dim3(256), 0, stream>>>(Wk, Wq, Wv, Wo, (__bf16*)d_ws);
    (void)hipFuncSetAttribute(reinterpret_cast<const void*>(&sapd_fused<true>),
                              hipFuncAttributeMaxDynamicSharedMemorySize, SMEM);
    sapd_fused<true><<<dim3(512), dim3(512), SMEM, stream>>>(
        S, bq, bk, bv, bo, Wq, Wk, Wv, Wo, lg, lb, (const __bf16*)d_ws, out);
  } else {
    (void)hipFuncSetAttribute(reinterpret_cast<const void*>(&sapd_fused<false>),
                              hipFuncAttributeMaxDynamicSharedMemorySize, SMEM);
    sapd_fused<false><<<dim3(512), dim3(512), SMEM, stream>>>(
        S, bq, bk, bv, bo, Wq, Wk, Wv, Wo, lg, lb, nullptr, out);
  }
}

// Round 4
// 72.789 us; speedup vs baseline: 1.0134x; 1.0134x over previous
//
#include <hip/hip_runtime.h>

#define DEV static __device__ __forceinline__

typedef __bf16 bf16x8 __attribute__((ext_vector_type(8)));
typedef float  f32x16 __attribute__((ext_vector_type(16)));

// 32x32 MFMA C/D row for reg r, lane-half hi (verified m74/m101)
DEV int rowmap(int r, int hi) { return (r & 3) + 8 * (r >> 2) + 4 * hi; }

// 256B-row tiles (W^T, Q): 16B-block XOR4 swizzle (full bank spread)
DEV int swzQ(int row, int col) {
  return row * 256 + (((((col >> 3) ^ (row & 15)) << 3) | (col & 7)) << 1);
}
// 512B-row tile (V^T [128 d][256 k]): XOR5
DEV int swzV(int d, int k) {
  return d * 512 + (((((k >> 3) ^ (d & 31)) << 3) | (k & 7)) << 1);
}

DEV unsigned pack2(float lo, float hi) {
  union { __bf16 h[2]; unsigned u; } x;
  x.h[0] = (__bf16)lo; x.h[1] = (__bf16)hi;
  return x.u;
}

// D-layout 16-row slab -> A/B fragment; half-swap via shfl_xor(.,32)+select.
DEV bf16x8 mk_frag(float d0, float d1, float d2, float d3,
                   float d4, float d5, float d6, float d7, int lane) {
  unsigned a0 = pack2(d0, d1), a1 = pack2(d2, d3);
  unsigned b0 = pack2(d4, d5), b1 = pack2(d6, d7);
  unsigned a0s = __shfl_xor(a0, 32), a1s = __shfl_xor(a1, 32);
  unsigned b0s = __shfl_xor(b0, 32), b1s = __shfl_xor(b1, 32);
  bool lo = lane < 32;
  union { unsigned u[4]; bf16x8 v; } r;
  r.u[0] = lo ? a0  : b0s;
  r.u[1] = lo ? a1  : b1s;
  r.u[2] = lo ? a0s : b0;
  r.u[3] = lo ? a1s : b1;
  return r.v;
}

DEV f32x16 fzero() {
  f32x16 z;
  #pragma unroll
  for (int i = 0; i < 16; ++i) z[i] = 0.f;
  return z;
}

// async global->LDS, 16B per lane, wave-uniform LDS base (m97 pattern)
DEV void gld16(const char* g, char* l) {
  __builtin_amdgcn_global_load_lds(
      (const __attribute__((address_space(1))) void*)g,
      (__attribute__((address_space(3))) void*)l, 16, 0, 0);
}

// fallback: stage fp32 W (row-major [e][d']) into LDS as swizzled W^T bf16
DEV void stage_w32(const float* __restrict__ W, char* dst, int tid) {
  #pragma unroll
  for (int it = 0; it < 32; ++it) {
    int idx = tid + it * 512;
    int e = idx >> 7, dp = idx & 127;
    *reinterpret_cast<__bf16*>(dst + swzQ(dp, e)) = (__bf16)W[idx];
  }
}

// prep: W fp32 [e][d'] -> bf16 W^T swizzled, packed [Wk|Wq|Wv|Wo] in d_ws
__global__ void prep_wt(const float* __restrict__ Wk, const float* __restrict__ Wq,
                        const float* __restrict__ Wv, const float* __restrict__ Wo,
                        __bf16* __restrict__ wt) {
  int idx = blockIdx.x * 256 + threadIdx.x;   // 0..65535
  const float* W[4] = {Wk, Wq, Wv, Wo};
  int m = idx >> 14, rem = idx & 16383;
  int e = rem >> 7, dp = rem & 127;           // read W[e][dp], coalesced in dp
  wt[m * 16384 + (swzQ(dp, e) >> 1)] = (__bf16)W[m][rem];
}

template<bool WS>
__global__ __launch_bounds__(512, 2)
void sapd_fused(const float* __restrict__ S,
                const float* __restrict__ bq, const float* __restrict__ bk,
                const float* __restrict__ bv, const float* __restrict__ bo,
                const float* __restrict__ Wq, const float* __restrict__ Wk,
                const float* __restrict__ Wv, const float* __restrict__ Wo,
                const float* __restrict__ lg, const float* __restrict__ lb,
                const __bf16* __restrict__ wt,
                float* __restrict__ out)
{
  extern __shared__ char smem[];
  char* RA = smem;           // 64K: Wv(lo) -> V^T [128 d][256 k]
  char* RB = smem + 65536;   // 64K: Wk(lo)|Wq(hi) -> Q [256][128] -> Wo(lo)

  const int tid  = threadIdx.x;
  const int lane = tid & 63;
  const int w    = tid >> 6;    // wave 0..7 owns output rows [32w, 32w+32)
  const int ml   = lane & 31;
  const int hi   = lane >> 5;
  const size_t sbase = (size_t)blockIdx.x * (256 * 128);
  const char* wsc = (const char*)wt;

  // ---- stage Wk|Wq -> RB, Wv -> RA.lo (96 x 1KB chunks, async DMA) ----
  if (WS) {
    #pragma unroll
    for (int j = 0; j < 12; ++j) {
      int c = w + 8 * j;  // wave-uniform
      char* dst = (c < 64) ? (RB + c * 1024) : (RA + (c - 64) * 1024);
      gld16(wsc + c * 1024 + lane * 16, dst);
    }
  } else {
    stage_w32(Wk, RB, tid);
    stage_w32(Wq, RB + 32768, tid);
    stage_w32(Wv, RA, tid);
  }

  // ---- S row-fragments (operand for the three projections) ----
  bf16x8 sfrag[8];
  {
    const float* srow = S + sbase + (size_t)(32 * w + ml) * 128;
    #pragma unroll
    for (int kk = 0; kk < 8; ++kk) {
      float4 a = *reinterpret_cast<const float4*>(srow + 16 * kk + 8 * hi);
      float4 b = *reinterpret_cast<const float4*>(srow + 16 * kk + 8 * hi + 4);
      bf16x8 f;
      f[0] = (__bf16)a.x; f[1] = (__bf16)a.y; f[2] = (__bf16)a.z; f[3] = (__bf16)a.w;
      f[4] = (__bf16)b.x; f[5] = (__bf16)b.y; f[6] = (__bf16)b.z; f[7] = (__bf16)b.w;
      sfrag[kk] = f;
    }
  }
  __syncthreads();  // #1: Wk|Wq|Wv staged

  // ---- K-proj SWAPPED (reads RB.lo): accK lane=j, rows=d' -> kfrag regs ----
  bf16x8 kfrag[8];
  {
    f32x16 accK[4];
    #pragma unroll
    for (int t = 0; t < 4; ++t) accK[t] = fzero();
    #pragma unroll
    for (int kk = 0; kk < 8; ++kk) {
      #pragma unroll
      for (int t = 0; t < 4; ++t) {
        bf16x8 wf = *reinterpret_cast<const bf16x8*>(
            RB + swzQ(32 * t + ml, 16 * kk + 8 * hi));
        accK[t] = __builtin_amdgcn_mfma_f32_32x32x16_bf16(wf, sfrag[kk], accK[t], 0, 0, 0);
      }
    }
    #pragma unroll
    for (int t = 0; t < 4; ++t) {
      #pragma unroll
      for (int r = 0; r < 16; ++r) accK[t][r] += bk[32 * t + rowmap(r, hi)];
      kfrag[2 * t]     = mk_frag(accK[t][0], accK[t][1], accK[t][2], accK[t][3],
                                 accK[t][4], accK[t][5], accK[t][6], accK[t][7], lane);
      kfrag[2 * t + 1] = mk_frag(accK[t][8], accK[t][9], accK[t][10], accK[t][11],
                                 accK[t][12], accK[t][13], accK[t][14], accK[t][15], lane);
    }
  }

  // ---- V-proj (reads RA.lo), acc dies into V^T write after barrier ----
  {
    f32x16 accV[4];
    #pragma unroll
    for (int t = 0; t < 4; ++t) accV[t] = fzero();
    #pragma unroll
    for (int kk = 0; kk < 8; ++kk) {
      #pragma unroll
      for (int t = 0; t < 4; ++t) {
        bf16x8 wf = *reinterpret_cast<const bf16x8*>(
            RA + swzQ(32 * t + ml, 16 * kk + 8 * hi));
        accV[t] = __builtin_amdgcn_mfma_f32_32x32x16_bf16(sfrag[kk], wf, accV[t], 0, 0, 0);
      }
    }
    __syncthreads();  // #2: Wk+Wv reads done everywhere; RA reusable
    #pragma unroll
    for (int t = 0; t < 4; ++t) {
      float bb = bv[32 * t + ml];
      int d = 32 * t + ml;
      #pragma unroll
      for (int p = 0; p < 8; ++p) {
        int k = 32 * w + rowmap(2 * p, hi);  // even; pair (k, k+1)
        *reinterpret_cast<unsigned*>(RA + swzV(d, k)) =
            pack2(accV[t][2 * p] + bb, accV[t][2 * p + 1] + bb);
      }
    }
  }

  // ---- Q-proj (reads RB.hi, still intact) ----
  {
    f32x16 accQ[4];
    #pragma unroll
    for (int t = 0; t < 4; ++t) accQ[t] = fzero();
    #pragma unroll
    for (int kk = 0; kk < 8; ++kk) {
      #pragma unroll
      for (int t = 0; t < 4; ++t) {
        bf16x8 wf = *reinterpret_cast<const bf16x8*>(
            RB + 32768 + swzQ(32 * t + ml, 16 * kk + 8 * hi));
        accQ[t] = __builtin_amdgcn_mfma_f32_32x32x16_bf16(sfrag[kk], wf, accQ[t], 0, 0, 0);
      }
    }
    __syncthreads();  // #3: Wq reads done everywhere; RB reusable (V^T writes also done)
    #pragma unroll
    for (int t = 0; t < 4; ++t) {
      float bb = bq[32 * t + ml];
      #pragma unroll
      for (int r = 0; r < 16; ++r)
        *reinterpret_cast<__bf16*>(
            RB + swzQ(32 * w + rowmap(r, hi), 32 * t + ml)) =
            (__bf16)(accQ[t][r] + bb);
    }
  }
  __syncthreads();  // #4: Q (RB) + V^T (RA) visible

  // ---- attention: sa = scores^T tile (lane=j), relu, ctx^T += V^T·P^T ----
  f32x16 ctx[4];
  #pragma unroll
  for (int m = 0; m < 4; ++m) ctx[m] = fzero();
  const float SC = 0.088388347648318447f;  // 1/sqrt(128)

  #pragma unroll 2
  for (int kt = 0; kt < 8; ++kt) {
    f32x16 sa = fzero();
    __builtin_amdgcn_s_setprio(1);
    #pragma unroll
    for (int kk = 0; kk < 8; ++kk) {
      bf16x8 qf = *reinterpret_cast<const bf16x8*>(
          RB + swzQ(32 * kt + ml, 16 * kk + 8 * hi));
      sa = __builtin_amdgcn_mfma_f32_32x32x16_bf16(qf, kfrag[kk], sa, 0, 0, 0);
    }
    __builtin_amdgcn_s_setprio(0);
    float p[16];
    #pragma unroll
    for (int r = 0; r < 16; ++r) p[r] = fmaxf(sa[r] * SC, 0.f);
    bf16x8 pf0 = mk_frag(p[0], p[1], p[2], p[3], p[4], p[5], p[6], p[7], lane);
    bf16x8 pf1 = mk_frag(p[8], p[9], p[10], p[11], p[12], p[13], p[14], p[15], lane);
    __builtin_amdgcn_s_setprio(1);
    #pragma unroll
    for (int m = 0; m < 4; ++m) {
      bf16x8 vf0 = *reinterpret_cast<const bf16x8*>(
          RA + swzV(32 * m + ml, 32 * kt + 8 * hi));
      ctx[m] = __builtin_amdgcn_mfma_f32_32x32x16_bf16(vf0, pf0, ctx[m], 0, 0, 0);
      bf16x8 vf1 = *reinterpret_cast<const bf16x8*>(
          RA + swzV(32 * m + ml, 32 * kt + 16 + 8 * hi));
      ctx[m] = __builtin_amdgcn_mfma_f32_32x32x16_bf16(vf1, pf1, ctx[m], 0, 0, 0);
    }
    __builtin_amdgcn_s_setprio(0);

    if (kt == 3) {
      // Q rows 0..127 (RB.lo) are dead for every wave: overlap Wo staging
      __syncthreads();  // #5
      if (WS) {
        #pragma unroll
        for (int j = 0; j < 4; ++j) {
          int c = w + 8 * j;
          gld16(wsc + 98304 + c * 1024 + lane * 16, RB + c * 1024);
        }
      } else {
        stage_w32(Wo, RB, tid);
      }
    }
  }

  // ---- ctx^T -> A-frags; issue residual loads (drain under out-proj) ----
  bf16x8 cf[8];
  #pragma unroll
  for (int m = 0; m < 4; ++m) {
    cf[2 * m]     = mk_frag(ctx[m][0], ctx[m][1], ctx[m][2], ctx[m][3],
                            ctx[m][4], ctx[m][5], ctx[m][6], ctx[m][7], lane);
    cf[2 * m + 1] = mk_frag(ctx[m][8], ctx[m][9], ctx[m][10], ctx[m][11],
                            ctx[m][12], ctx[m][13], ctx[m][14], ctx[m][15], lane);
  }
  float resv[4][16];
  #pragma unroll
  for (int t = 0; t < 4; ++t) {
    #pragma unroll
    for (int r = 0; r < 16; ++r)
      resv[t][r] = S[sbase + (size_t)(32 * w + rowmap(r, hi)) * 128 + 32 * t + ml];
  }
  __syncthreads();  // #6: Wo DMA drained; all Q reads done

  // ---- out-proj (reads RB.lo = Wo^T) ----
  f32x16 oa[4];
  #pragma unroll
  for (int t = 0; t < 4; ++t) oa[t] = fzero();
  #pragma unroll
  for (int kk = 0; kk < 8; ++kk) {
    #pragma unroll
    for (int t = 0; t < 4; ++t) {
      bf16x8 wf = *reinterpret_cast<const bf16x8*>(
          RB + swzQ(32 * t + ml, 16 * kk + 8 * hi));
      oa[t] = __builtin_amdgcn_mfma_f32_32x32x16_bf16(cf[kk], wf, oa[t], 0, 0, 0);
    }
  }

  // ---- epilogue: +bo, +residual(fp32), LayerNorm, store ----
  float gg[4], lbv[4], bov[4];
  #pragma unroll
  for (int t = 0; t < 4; ++t) {
    gg[t]  = lg[32 * t + ml];
    lbv[t] = lb[32 * t + ml];
    bov[t] = bo[32 * t + ml];
  }
  float sum[16], ssq[16];
  #pragma unroll
  for (int r = 0; r < 16; ++r) { sum[r] = 0.f; ssq[r] = 0.f; }
  #pragma unroll
  for (int t = 0; t < 4; ++t) {
    #pragma unroll
    for (int r = 0; r < 16; ++r) {
      float x = oa[t][r] + bov[t] + resv[t][r];
      oa[t][r] = x;
      sum[r] += x;
      ssq[r] += x * x;
    }
  }
  #pragma unroll
  for (int r = 0; r < 16; ++r) {
    float s_ = sum[r], q_ = ssq[r];
    #pragma unroll
    for (int m = 1; m <= 16; m <<= 1) {
      s_ += __shfl_xor(s_, m);
      q_ += __shfl_xor(q_, m);
    }
    float mu = s_ * (1.f / 128.f);
    float var = q_ * (1.f / 128.f) - mu * mu;
    float rs = rsqrtf(var + 1e-5f);
    float* orow = out + sbase + (size_t)(32 * w + rowmap(r, hi)) * 128;
    #pragma unroll
    for (int t = 0; t < 4; ++t)
      orow[32 * t + ml] = (oa[t][r] - mu) * rs * gg[t] + lbv[t];
  }
}

extern "C" void kernel_launch(void* const* d_in, const int* in_sizes, int n_in,
                              void* d_out, int out_size, void* d_ws, size_t ws_size,
                              hipStream_t stream) {
  (void)in_sizes; (void)n_in; (void)out_size;
  const float* S  = (const float*)d_in[1];
  const float* Wq = (const float*)d_in[2];
  const float* bq = (const float*)d_in[3];
  const float* Wk = (const float*)d_in[4];
  const float* bk = (const float*)d_in[5];
  const float* Wv = (const float*)d_in[6];
  const float* bv = (const float*)d_in[7];
  const float* Wo = (const float*)d_in[8];
  const float* bo = (const float*)d_in[9];
  const float* lg = (const float*)d_in[10];
  const float* lb = (const float*)d_in[11];
  float* out = (float*)d_out;

  constexpr int SMEM = 131072;  // 128 KiB dynamic LDS -> 1 block/CU (structural)
  bool use_ws = (d_ws != nullptr) && (ws_size >= 131072);
  if (use_ws) {
    prep_wt<<<dim3(256), dim3(256), 0, stream>>>(Wk, Wq, Wv, Wo, (__bf16*)d_ws);
    (void)hipFuncSetAttribute(reinterpret_cast<const void*>(&sapd_fused<true>),
                              hipFuncAttributeMaxDynamicSharedMemorySize, SMEM);
    sapd_fused<true><<<dim3(512), dim3(512), SMEM, stream>>>(
        S, bq, bk, bv, bo, Wq, Wk, Wv, Wo, lg, lb, (const __bf16*)d_ws, out);
  } else {
    (void)hipFuncSetAttribute(reinterpret_cast<const void*>(&sapd_fused<false>),
                              hipFuncAttributeMaxDynamicSharedMemorySize, SMEM);
    sapd_fused<false><<<dim3(512), dim3(512), SMEM, stream>>>(
        S, bq, bk, bv, bo, Wq, Wk, Wv, Wo, lg, lb, nullptr, out);
  }
}